// Round 1
// baseline (605.806 us; speedup 1.0000x reference)
//
#include <hip/hip_runtime.h>
#include <math.h>

// ---------------- CSR construction ----------------

__global__ void zero_kernel(int* __restrict__ p, int n) {
  int i = blockIdx.x * blockDim.x + threadIdx.x;
  if (i < n) p[i] = 0;
}

__global__ void hist_kernel(const int* __restrict__ dst, int* __restrict__ counts, int E) {
  int e = blockIdx.x * blockDim.x + threadIdx.x;
  if (e < E) atomicAdd(&counts[dst[e]], 1);
}

// Single-block exclusive scan over node degrees -> row_ptr, and init cursor.
__global__ __launch_bounds__(1024) void scan_kernel(const int* __restrict__ counts,
                                                    int* __restrict__ row_ptr,
                                                    int* __restrict__ cursor, int n) {
  constexpr int T = 1024;
  int tid = threadIdx.x;
  int chunk = (n + T - 1) / T;
  int beg = tid * chunk;
  int end = beg + chunk;
  if (end > n) end = n;
  if (beg > n) beg = n;
  int sum = 0;
  for (int i = beg; i < end; ++i) sum += counts[i];
  __shared__ int s[T];
  s[tid] = sum;
  __syncthreads();
  // Hillis-Steele inclusive scan of per-thread sums
  for (int off = 1; off < T; off <<= 1) {
    int t = (tid >= off) ? s[tid - off] : 0;
    __syncthreads();
    s[tid] += t;
    __syncthreads();
  }
  int run = s[tid] - sum;  // exclusive prefix of this thread's chunk
  for (int i = beg; i < end; ++i) {
    row_ptr[i] = run;
    cursor[i] = run;
    run += counts[i];
  }
  if (tid == T - 1) row_ptr[n] = s[T - 1];
}

__global__ void scatter_kernel(const int* __restrict__ src, const int* __restrict__ dst,
                               int* __restrict__ cursor, int* __restrict__ col, int E) {
  int e = blockIdx.x * blockDim.x + threadIdx.x;
  if (e < E) {
    int d = dst[e];
    int p = atomicAdd(&cursor[d], 1);
    col[p] = src[e];
  }
}

// ---------------- Dense GEMM: out[N,M] = A[N,K] @ W[K,M] ----------------
// W staged fully in LDS (<=48KB). 64 rows per block, 256 threads,
// each thread computes 4 rows x CJ cols.

template <int K, int M>
__global__ __launch_bounds__(256) void gemm_kernel(const float* __restrict__ A,
                                                   const float* __restrict__ W,
                                                   float* __restrict__ out, int N) {
  constexpr int CJ = (M + 15) / 16;  // cols per thread
  constexpr int MP = 16 * CJ;        // padded col count
  __shared__ float sW[K * MP];
  int tid = threadIdx.x;
  for (int idx = tid; idx < K * MP; idx += 256) {
    int k = idx / MP;
    int c = idx - k * MP;
    sW[idx] = (c < M) ? W[k * M + c] : 0.f;
  }
  __syncthreads();

  int ct = tid & 15;
  int rt = tid >> 4;
  int row0 = blockIdx.x * 64;

  float acc[4][CJ];
#pragma unroll
  for (int i = 0; i < 4; ++i)
#pragma unroll
    for (int j = 0; j < CJ; ++j) acc[i][j] = 0.f;

  int rows[4];
  bool rv[4];
#pragma unroll
  for (int i = 0; i < 4; ++i) {
    rows[i] = row0 + rt + 16 * i;
    rv[i] = rows[i] < N;
  }

  for (int k = 0; k < K; k += 4) {
    float4 xv[4];
#pragma unroll
    for (int i = 0; i < 4; ++i) {
      xv[i] = rv[i] ? *(const float4*)(A + (size_t)rows[i] * K + k)
                    : make_float4(0.f, 0.f, 0.f, 0.f);
    }
#pragma unroll
    for (int kk = 0; kk < 4; ++kk) {
      float w[CJ];
#pragma unroll
      for (int j = 0; j < CJ; ++j) w[j] = sW[(k + kk) * MP + ct * CJ + j];
#pragma unroll
      for (int i = 0; i < 4; ++i) {
        float xs = (&xv[i].x)[kk];
#pragma unroll
        for (int j = 0; j < CJ; ++j) acc[i][j] = fmaf(xs, w[j], acc[i][j]);
      }
    }
  }

#pragma unroll
  for (int i = 0; i < 4; ++i) {
    if (!rv[i]) continue;
#pragma unroll
    for (int j = 0; j < CJ; ++j) {
      int c = ct * CJ + j;
      if (c < M) out[(size_t)rows[i] * M + c] = acc[i][j];
    }
  }
}

// ---------------- Aggregation (gather-sum over CSR) ----------------
// One block per dst node; thread f handles feature f.

template <int F>
__global__ void agg_relu_kernel(const float* __restrict__ t, const int* __restrict__ row_ptr,
                                const int* __restrict__ col, const float* __restrict__ bias,
                                float* __restrict__ out) {
  int node = blockIdx.x;
  int f = threadIdx.x;  // blockDim == F
  int beg = row_ptr[node];
  int end = row_ptr[node + 1];
  float acc = 0.f;
  for (int e = beg; e < end; ++e) {
    int s = col[e];
    acc += t[(size_t)s * F + f];
  }
  float v = acc + bias[f];
  out[(size_t)node * F + f] = v > 0.f ? v : 0.f;
}

// Layer-3 aggregation fused with bias + log_softmax over 40 classes.
// One wave (64 threads) per node; lanes 0..39 hold the classes.
__global__ void agg_lsm_kernel(const float* __restrict__ t, const int* __restrict__ row_ptr,
                               const int* __restrict__ col, const float* __restrict__ bias,
                               float* __restrict__ out) {
  int node = blockIdx.x;
  int f = threadIdx.x;  // 0..63
  int beg = row_ptr[node];
  int end = row_ptr[node + 1];
  float acc = 0.f;
  for (int e = beg; e < end; ++e) {
    int s = col[e];
    if (f < 40) acc += t[(size_t)s * 40 + f];
  }
  float v = (f < 40) ? acc + bias[f] : -__builtin_inff();
  float m = v;
#pragma unroll
  for (int off = 32; off; off >>= 1) m = fmaxf(m, __shfl_xor(m, off, 64));
  float ex = (f < 40) ? __expf(v - m) : 0.f;
  float ssum = ex;
#pragma unroll
  for (int off = 32; off; off >>= 1) ssum += __shfl_xor(ssum, off, 64);
  if (f < 40) out[(size_t)node * 40 + f] = v - m - __logf(ssum);
}

// ---------------- Launch ----------------

extern "C" void kernel_launch(void* const* d_in, const int* in_sizes, int n_in,
                              void* d_out, int out_size, void* d_ws, size_t ws_size,
                              hipStream_t stream) {
  const float* x  = (const float*)d_in[0];   // [N,128]
  const float* W1 = (const float*)d_in[1];   // [128,96]
  const float* b1 = (const float*)d_in[2];   // [96]
  const float* W2 = (const float*)d_in[3];   // [96,96]
  const float* b2 = (const float*)d_in[4];   // [96]
  const float* W3 = (const float*)d_in[5];   // [96,40]
  const float* b3 = (const float*)d_in[6];   // [40]
  const int* edge = (const int*)d_in[7];     // [2,E] int32 (see risk note)

  int N = in_sizes[0] / 128;  // 50000
  int E = in_sizes[7] / 2;    // 800000
  const int* srcp = edge;
  const int* dstp = edge + E;

  char* p = (char*)d_ws;
  auto alloc = [&](size_t bytes) {
    char* r = p;
    p += (bytes + 255) & ~size_t(255);
    return r;
  };
  int* counts   = (int*)alloc((size_t)N * 4);
  int* cursor   = (int*)alloc((size_t)N * 4);
  int* row_ptr  = (int*)alloc((size_t)(N + 1) * 4);
  int* col      = (int*)alloc((size_t)E * 4);
  float* Tbuf   = (float*)alloc((size_t)N * 96 * 4);
  float* Hbuf   = (float*)alloc((size_t)N * 96 * 4);

  // CSR build (per-call; workspace is poisoned before every launch)
  zero_kernel<<<(N + 255) / 256, 256, 0, stream>>>(counts, N);
  hist_kernel<<<(E + 255) / 256, 256, 0, stream>>>(dstp, counts, E);
  scan_kernel<<<1, 1024, 0, stream>>>(counts, row_ptr, cursor, N);
  scatter_kernel<<<(E + 255) / 256, 256, 0, stream>>>(srcp, dstp, cursor, col, E);

  int gblocks = (N + 63) / 64;
  // Layer 1: t = x@W1 ; h = relu(agg(t)+b1)
  gemm_kernel<128, 96><<<gblocks, 256, 0, stream>>>(x, W1, Tbuf, N);
  agg_relu_kernel<96><<<N, 96, 0, stream>>>(Tbuf, row_ptr, col, b1, Hbuf);
  // Layer 2
  gemm_kernel<96, 96><<<gblocks, 256, 0, stream>>>(Hbuf, W2, Tbuf, N);
  agg_relu_kernel<96><<<N, 96, 0, stream>>>(Tbuf, row_ptr, col, b2, Hbuf);
  // Layer 3 + log_softmax
  gemm_kernel<96, 40><<<gblocks, 256, 0, stream>>>(Hbuf, W3, Tbuf, N);
  agg_lsm_kernel<<<N, 64, 0, stream>>>(Tbuf, row_ptr, col, b3, (float*)d_out);
}

// Round 2
// 421.525 us; speedup vs baseline: 1.4372x; 1.4372x over previous
//
#include <hip/hip_runtime.h>
#include <math.h>

// ---------------- CSR construction ----------------

__global__ void zero_kernel(int* __restrict__ p, int n) {
  int i = blockIdx.x * blockDim.x + threadIdx.x;
  if (i < n) p[i] = 0;
}

__global__ void hist_kernel(const int* __restrict__ dst, int* __restrict__ counts, int E) {
  int e = blockIdx.x * blockDim.x + threadIdx.x;
  if (e < E) atomicAdd(&counts[dst[e]], 1);
}

// --- Hierarchical scan: 1024 elems per 256-thread block ---
constexpr int SCAN_T = 256;
constexpr int SCAN_E = 4;
constexpr int SCAN_B = SCAN_T * SCAN_E;  // 1024

__global__ __launch_bounds__(SCAN_T) void scan_part1(const int* __restrict__ counts,
                                                     int* __restrict__ bsum, int n) {
  int tid = threadIdx.x;
  int base = blockIdx.x * SCAN_B + tid * SCAN_E;
  int s = 0;
#pragma unroll
  for (int i = 0; i < SCAN_E; ++i) {
    int idx = base + i;
    if (idx < n) s += counts[idx];
  }
  __shared__ int sm[SCAN_T];
  sm[tid] = s;
  __syncthreads();
  for (int off = SCAN_T / 2; off > 0; off >>= 1) {
    if (tid < off) sm[tid] += sm[tid + off];
    __syncthreads();
  }
  if (tid == 0) bsum[blockIdx.x] = sm[0];
}

// single block; nb <= 256. Converts bsum to exclusive offsets, writes row_ptr[n]=total.
__global__ __launch_bounds__(256) void scan_part2(int* __restrict__ bsum,
                                                  int* __restrict__ row_ptr, int nb, int n) {
  __shared__ int sm[256];
  int tid = threadIdx.x;
  int v = (tid < nb) ? bsum[tid] : 0;
  sm[tid] = v;
  __syncthreads();
  for (int off = 1; off < 256; off <<= 1) {
    int t = (tid >= off) ? sm[tid - off] : 0;
    __syncthreads();
    sm[tid] += t;
    __syncthreads();
  }
  if (tid < nb) bsum[tid] = sm[tid] - v;  // exclusive block offsets
  if (tid == 255) row_ptr[n] = sm[255];
}

__global__ __launch_bounds__(SCAN_T) void scan_part3(const int* __restrict__ counts,
                                                     const int* __restrict__ bsum,
                                                     int* __restrict__ row_ptr,
                                                     int* __restrict__ cursor, int n) {
  int tid = threadIdx.x;
  int base = blockIdx.x * SCAN_B + tid * SCAN_E;
  int vals[SCAN_E];
  int s = 0;
#pragma unroll
  for (int i = 0; i < SCAN_E; ++i) {
    int idx = base + i;
    vals[i] = (idx < n) ? counts[idx] : 0;
    s += vals[i];
  }
  __shared__ int sm[SCAN_T];
  sm[tid] = s;
  __syncthreads();
  for (int off = 1; off < SCAN_T; off <<= 1) {
    int t = (tid >= off) ? sm[tid - off] : 0;
    __syncthreads();
    sm[tid] += t;
    __syncthreads();
  }
  int run = bsum[blockIdx.x] + sm[tid] - s;  // exclusive prefix for this thread
#pragma unroll
  for (int i = 0; i < SCAN_E; ++i) {
    int idx = base + i;
    if (idx < n) {
      row_ptr[idx] = run;
      cursor[idx] = run;
      run += vals[i];
    }
  }
}

__global__ void scatter_kernel(const int* __restrict__ src, const int* __restrict__ dst,
                               int* __restrict__ cursor, int* __restrict__ col, int E) {
  int e = blockIdx.x * blockDim.x + threadIdx.x;
  if (e < E) {
    int d = dst[e];
    int p = atomicAdd(&cursor[d], 1);
    col[p] = src[e];
  }
}

// ---------------- Dense GEMM: out[N,M] = A[N,K] @ W[K,M] ----------------

template <int K, int M>
__global__ __launch_bounds__(256) void gemm_kernel(const float* __restrict__ A,
                                                   const float* __restrict__ W,
                                                   float* __restrict__ out, int N) {
  constexpr int CJ = (M + 15) / 16;  // cols per thread
  constexpr int MP = 16 * CJ;        // padded col count
  __shared__ float sW[K * MP];
  int tid = threadIdx.x;
  for (int idx = tid; idx < K * MP; idx += 256) {
    int k = idx / MP;
    int c = idx - k * MP;
    sW[idx] = (c < M) ? W[k * M + c] : 0.f;
  }
  __syncthreads();

  int ct = tid & 15;
  int rt = tid >> 4;
  int row0 = blockIdx.x * 64;

  float acc[4][CJ];
#pragma unroll
  for (int i = 0; i < 4; ++i)
#pragma unroll
    for (int j = 0; j < CJ; ++j) acc[i][j] = 0.f;

  int rows[4];
  bool rv[4];
#pragma unroll
  for (int i = 0; i < 4; ++i) {
    rows[i] = row0 + rt + 16 * i;
    rv[i] = rows[i] < N;
  }

  for (int k = 0; k < K; k += 4) {
    float4 xv[4];
#pragma unroll
    for (int i = 0; i < 4; ++i) {
      xv[i] = rv[i] ? *(const float4*)(A + (size_t)rows[i] * K + k)
                    : make_float4(0.f, 0.f, 0.f, 0.f);
    }
#pragma unroll
    for (int kk = 0; kk < 4; ++kk) {
      float w[CJ];
#pragma unroll
      for (int j = 0; j < CJ; ++j) w[j] = sW[(k + kk) * MP + ct * CJ + j];
#pragma unroll
      for (int i = 0; i < 4; ++i) {
        float xs = (&xv[i].x)[kk];
#pragma unroll
        for (int j = 0; j < CJ; ++j) acc[i][j] = fmaf(xs, w[j], acc[i][j]);
      }
    }
  }

#pragma unroll
  for (int i = 0; i < 4; ++i) {
    if (!rv[i]) continue;
#pragma unroll
    for (int j = 0; j < CJ; ++j) {
      int c = ct * CJ + j;
      if (c < M) out[(size_t)rows[i] * M + c] = acc[i][j];
    }
  }
}

// ---------------- Aggregation (gather-sum over CSR), float4 ----------------
// Thread = (node, chunk): chunk c covers features 4c..4c+3. F/4 threads per node,
// zero idle lanes. Intra-wave degree divergence ~2-3 nodes/wave is the cost.

template <int F>
__global__ void agg_relu_v4(const float* __restrict__ t, const int* __restrict__ row_ptr,
                            const int* __restrict__ col, const float* __restrict__ bias,
                            float* __restrict__ out, int N) {
  constexpr int C = F / 4;  // chunks per node (24 for F=96)
  int gid = blockIdx.x * blockDim.x + threadIdx.x;
  int node = gid / C;
  int c = gid - node * C;
  if (node >= N) return;
  int beg = row_ptr[node];
  int end = row_ptr[node + 1];
  const float* tc = t + 4 * c;
  float4 acc = make_float4(0.f, 0.f, 0.f, 0.f);
  for (int e = beg; e < end; ++e) {
    int s = col[e];
    float4 v = *(const float4*)(tc + (size_t)s * F);
    acc.x += v.x;
    acc.y += v.y;
    acc.z += v.z;
    acc.w += v.w;
  }
  float4 b = ((const float4*)bias)[c];
  acc.x = fmaxf(acc.x + b.x, 0.f);
  acc.y = fmaxf(acc.y + b.y, 0.f);
  acc.z = fmaxf(acc.z + b.z, 0.f);
  acc.w = fmaxf(acc.w + b.w, 0.f);
  *(float4*)(out + (size_t)node * F + 4 * c) = acc;
}

// Layer-3 aggregation fused with bias + log_softmax over 40 classes.
// 16-lane group per node; lanes 0..9 each hold a float4 (4 classes).
__global__ void agg_lsm_v4(const float* __restrict__ t, const int* __restrict__ row_ptr,
                           const int* __restrict__ col, const float* __restrict__ bias,
                           float* __restrict__ out, int N) {
  int tid = threadIdx.x;
  int node = blockIdx.x * 16 + (tid >> 4);
  int c = tid & 15;  // 0..9 active
  bool act = (c < 10) && (node < N);
  int ceff = (c < 10) ? c : 0;
  int beg = 0, end = 0;
  if (node < N) {
    beg = row_ptr[node];
    end = row_ptr[node + 1];
  }
  const float* tc = t + 4 * ceff;
  float4 acc = make_float4(0.f, 0.f, 0.f, 0.f);
  if (act) {
    for (int e = beg; e < end; ++e) {
      int s = col[e];
      float4 v = *(const float4*)(tc + (size_t)s * 40);
      acc.x += v.x;
      acc.y += v.y;
      acc.z += v.z;
      acc.w += v.w;
    }
  }
  float4 b = ((const float4*)bias)[ceff];
  float v0 = acc.x + b.x, v1 = acc.y + b.y, v2 = acc.z + b.z, v3 = acc.w + b.w;
  float m = act ? fmaxf(fmaxf(v0, v1), fmaxf(v2, v3)) : -__builtin_inff();
#pragma unroll
  for (int off = 8; off; off >>= 1) m = fmaxf(m, __shfl_xor(m, off, 64));
  float ex = act ? (__expf(v0 - m) + __expf(v1 - m) + __expf(v2 - m) + __expf(v3 - m)) : 0.f;
#pragma unroll
  for (int off = 8; off; off >>= 1) ex += __shfl_xor(ex, off, 64);
  if (act) {
    float l = m + __logf(ex);
    float* o = out + (size_t)node * 40 + 4 * c;
    o[0] = v0 - l;
    o[1] = v1 - l;
    o[2] = v2 - l;
    o[3] = v3 - l;
  }
}

// ---------------- Launch ----------------

extern "C" void kernel_launch(void* const* d_in, const int* in_sizes, int n_in,
                              void* d_out, int out_size, void* d_ws, size_t ws_size,
                              hipStream_t stream) {
  const float* x  = (const float*)d_in[0];   // [N,128]
  const float* W1 = (const float*)d_in[1];   // [128,96]
  const float* b1 = (const float*)d_in[2];   // [96]
  const float* W2 = (const float*)d_in[3];   // [96,96]
  const float* b2 = (const float*)d_in[4];   // [96]
  const float* W3 = (const float*)d_in[5];   // [96,40]
  const float* b3 = (const float*)d_in[6];   // [40]
  const int* edge = (const int*)d_in[7];     // [2,E] int32

  int N = in_sizes[0] / 128;  // 50000
  int E = in_sizes[7] / 2;    // 800000
  const int* srcp = edge;
  const int* dstp = edge + E;

  char* p = (char*)d_ws;
  auto alloc = [&](size_t bytes) {
    char* r = p;
    p += (bytes + 255) & ~size_t(255);
    return r;
  };
  int* counts  = (int*)alloc((size_t)N * 4);
  int* cursor  = (int*)alloc((size_t)N * 4);
  int* row_ptr = (int*)alloc((size_t)(N + 1) * 4);
  int* col     = (int*)alloc((size_t)E * 4);
  int* bsum    = (int*)alloc(256 * 4);
  float* Tbuf  = (float*)alloc((size_t)N * 96 * 4);
  float* Hbuf  = (float*)alloc((size_t)N * 96 * 4);

  int nsb = (N + SCAN_B - 1) / SCAN_B;  // 49 scan blocks

  // CSR build (per-call; workspace is re-poisoned before every launch)
  zero_kernel<<<(N + 255) / 256, 256, 0, stream>>>(counts, N);
  hist_kernel<<<(E + 255) / 256, 256, 0, stream>>>(dstp, counts, E);
  scan_part1<<<nsb, SCAN_T, 0, stream>>>(counts, bsum, N);
  scan_part2<<<1, 256, 0, stream>>>(bsum, row_ptr, nsb, N);
  scan_part3<<<nsb, SCAN_T, 0, stream>>>(counts, bsum, row_ptr, cursor, N);
  scatter_kernel<<<(E + 255) / 256, 256, 0, stream>>>(srcp, dstp, cursor, col, E);

  int gblocks = (N + 63) / 64;
  int aggblocks = (N * 24 + 255) / 256;
  // Layer 1: t = x@W1 ; h = relu(agg(t)+b1)
  gemm_kernel<128, 96><<<gblocks, 256, 0, stream>>>(x, W1, Tbuf, N);
  agg_relu_v4<96><<<aggblocks, 256, 0, stream>>>(Tbuf, row_ptr, col, b1, Hbuf, N);
  // Layer 2
  gemm_kernel<96, 96><<<gblocks, 256, 0, stream>>>(Hbuf, W2, Tbuf, N);
  agg_relu_v4<96><<<aggblocks, 256, 0, stream>>>(Tbuf, row_ptr, col, b2, Hbuf, N);
  // Layer 3 + log_softmax
  gemm_kernel<96, 40><<<gblocks, 256, 0, stream>>>(Hbuf, W3, Tbuf, N);
  agg_lsm_v4<<<(N + 15) / 16, 256, 0, stream>>>(Tbuf, row_ptr, col, b3, (float*)d_out, N);
}

// Round 3
// 313.069 us; speedup vs baseline: 1.9351x; 1.3464x over previous
//
#include <hip/hip_runtime.h>
#include <math.h>

typedef __attribute__((ext_vector_type(8))) short bf16x8;
typedef __attribute__((ext_vector_type(4))) float f32x4;

__device__ __forceinline__ unsigned short f2bf(float f) {
  unsigned u = __float_as_uint(f);
  u += 0x7fffu + ((u >> 16) & 1u);  // round-to-nearest-even
  return (unsigned short)(u >> 16);
}
__device__ __forceinline__ float bflo(unsigned u) { return __uint_as_float(u << 16); }
__device__ __forceinline__ float bfhi(unsigned u) { return __uint_as_float(u & 0xffff0000u); }

// ---------------- CSR construction ----------------

__global__ void zero_kernel(int* __restrict__ p, int n) {
  int i = blockIdx.x * blockDim.x + threadIdx.x;
  if (i < n) p[i] = 0;
}

__global__ void hist_kernel(const int* __restrict__ dst, int* __restrict__ counts, int E) {
  int e = blockIdx.x * blockDim.x + threadIdx.x;
  if (e < E) atomicAdd(&counts[dst[e]], 1);
}

constexpr int SCAN_T = 256;
constexpr int SCAN_E = 4;
constexpr int SCAN_B = SCAN_T * SCAN_E;  // 1024

__global__ __launch_bounds__(SCAN_T) void scan_part1(const int* __restrict__ counts,
                                                     int* __restrict__ bsum, int n) {
  int tid = threadIdx.x;
  int base = blockIdx.x * SCAN_B + tid * SCAN_E;
  int s = 0;
#pragma unroll
  for (int i = 0; i < SCAN_E; ++i) {
    int idx = base + i;
    if (idx < n) s += counts[idx];
  }
  __shared__ int sm[SCAN_T];
  sm[tid] = s;
  __syncthreads();
  for (int off = SCAN_T / 2; off > 0; off >>= 1) {
    if (tid < off) sm[tid] += sm[tid + off];
    __syncthreads();
  }
  if (tid == 0) bsum[blockIdx.x] = sm[0];
}

__global__ __launch_bounds__(256) void scan_part2(int* __restrict__ bsum,
                                                  int* __restrict__ row_ptr, int nb, int n) {
  __shared__ int sm[256];
  int tid = threadIdx.x;
  int v = (tid < nb) ? bsum[tid] : 0;
  sm[tid] = v;
  __syncthreads();
  for (int off = 1; off < 256; off <<= 1) {
    int t = (tid >= off) ? sm[tid - off] : 0;
    __syncthreads();
    sm[tid] += t;
    __syncthreads();
  }
  if (tid < nb) bsum[tid] = sm[tid] - v;
  if (tid == 255) row_ptr[n] = sm[255];
}

__global__ __launch_bounds__(SCAN_T) void scan_part3(const int* __restrict__ counts,
                                                     const int* __restrict__ bsum,
                                                     int* __restrict__ row_ptr,
                                                     int* __restrict__ cursor, int n) {
  int tid = threadIdx.x;
  int base = blockIdx.x * SCAN_B + tid * SCAN_E;
  int vals[SCAN_E];
  int s = 0;
#pragma unroll
  for (int i = 0; i < SCAN_E; ++i) {
    int idx = base + i;
    vals[i] = (idx < n) ? counts[idx] : 0;
    s += vals[i];
  }
  __shared__ int sm[SCAN_T];
  sm[tid] = s;
  __syncthreads();
  for (int off = 1; off < SCAN_T; off <<= 1) {
    int t = (tid >= off) ? sm[tid - off] : 0;
    __syncthreads();
    sm[tid] += t;
    __syncthreads();
  }
  int run = bsum[blockIdx.x] + sm[tid] - s;
#pragma unroll
  for (int i = 0; i < SCAN_E; ++i) {
    int idx = base + i;
    if (idx < n) {
      row_ptr[idx] = run;
      cursor[idx] = run;
      run += vals[i];
    }
  }
}

__global__ void scatter_kernel(const int* __restrict__ src, const int* __restrict__ dst,
                               int* __restrict__ cursor, int* __restrict__ col, int E) {
  int e = blockIdx.x * blockDim.x + threadIdx.x;
  if (e < E) {
    int d = dst[e];
    int p = atomicAdd(&cursor[d], 1);
    col[p] = src[e];
  }
}

// ---------------- W pre-pack into MFMA B-fragment order (bf16) ----------------
// Fragment (s, ct): lane l holds B[k = s*32 + (l>>4)*8 + j][col = ct*16 + (l&15)],
// j = 0..7, stored as 8 contiguous bf16 at Wp[((s*NCTT + ct)*64 + l)*8].
// One fused kernel packs W1 (KS=4,NCTT=6), W2 (3,6), W3 (3,3; cols >=40 zero).

__global__ void pack_w_kernel(const float* __restrict__ W1, const float* __restrict__ W2,
                              const float* __restrict__ W3, unsigned short* __restrict__ Wp1,
                              unsigned short* __restrict__ Wp2, unsigned short* __restrict__ Wp3) {
  int gid = blockIdx.x * blockDim.x + threadIdx.x;
  const float* W;
  unsigned short* Wp;
  int t, NCTT, M, MV;
  if (gid < 1536) {            // W1: 4 ksteps * 6 coltiles * 64 lanes
    W = W1; Wp = Wp1; t = gid; NCTT = 6; M = 96; MV = 96;
  } else if (gid < 2688) {     // W2: 3 * 6 * 64
    W = W2; Wp = Wp2; t = gid - 1536; NCTT = 6; M = 96; MV = 96;
  } else if (gid < 3264) {     // W3: 3 * 3 * 64 (padded to 48 cols)
    W = W3; Wp = Wp3; t = gid - 2688; NCTT = 3; M = 40; MV = 40;
  } else {
    return;
  }
  int lane = t & 63;
  int frag = t >> 6;
  int s = frag / NCTT;
  int ct = frag - s * NCTT;
  int colv = ct * 16 + (lane & 15);
  int k0 = s * 32 + (lane >> 4) * 8;
  unsigned short us[8];
#pragma unroll
  for (int j = 0; j < 8; ++j) {
    float v = (colv < MV) ? W[(k0 + j) * M + colv] : 0.f;
    us[j] = f2bf(v);
  }
  union { unsigned short s[8]; uint4 u; } pk;
#pragma unroll
  for (int j = 0; j < 8; ++j) pk.s[j] = us[j];
  ((uint4*)Wp)[t] = pk.u;
}

// ---------------- MFMA GEMM: out[N, MVALID] = A[N, K] @ W[K, MVALID] ----------------
// Wave computes a 16-row x 48-col tile. B-frags register-resident. No LDS.
// AF32: A is f32 (convert to bf16 in-flight); else A is bf16 (ushort).
// OUTBF16: write bf16, else f32. blockIdx.y = column group (48 cols each).

template <int KSTEPS, int NCTT, bool AF32, bool OUTBF16, int MOUT, int MVALID>
__global__ __launch_bounds__(256) void mfma_gemm(const void* __restrict__ Aptr,
                                                 const unsigned short* __restrict__ Wp,
                                                 void* __restrict__ outp, int N) {
  constexpr int NCT = 3;
  constexpr int K = KSTEPS * 32;
  int wid = threadIdx.x >> 6;
  int lane = threadIdx.x & 63;
  int rt = blockIdx.x * 4 + wid;
  if (rt * 16 >= N) return;
  int g = blockIdx.y;
  int quad = lane >> 4;
  int lm = lane & 15;

  // B fragments (loop-invariant, from packed W)
  union BU { uint4 u; bf16x8 v; };
  bf16x8 bfrag[KSTEPS][NCT];
  const uint4* wp4 = (const uint4*)Wp;
#pragma unroll
  for (int s = 0; s < KSTEPS; ++s)
#pragma unroll
    for (int c = 0; c < NCT; ++c) {
      BU bu;
      bu.u = wp4[(s * NCTT + g * NCT + c) * 64 + lane];
      bfrag[s][c] = bu.v;
    }

  f32x4 acc[NCT];
#pragma unroll
  for (int c = 0; c < NCT; ++c) acc[c] = (f32x4){0.f, 0.f, 0.f, 0.f};

  int row = rt * 16 + lm;
  if (row >= N) row = N - 1;  // safe duplicate read; epilogue guards rows

#pragma unroll
  for (int s = 0; s < KSTEPS; ++s) {
    int k0 = s * 32 + quad * 8;
    bf16x8 afrag;
    if (AF32) {
      const float* Af = (const float*)Aptr + (size_t)row * K + k0;
      float4 x0 = *(const float4*)(Af);
      float4 x1 = *(const float4*)(Af + 4);
      union { unsigned short s[8]; bf16x8 v; } au;
      au.s[0] = f2bf(x0.x); au.s[1] = f2bf(x0.y); au.s[2] = f2bf(x0.z); au.s[3] = f2bf(x0.w);
      au.s[4] = f2bf(x1.x); au.s[5] = f2bf(x1.y); au.s[6] = f2bf(x1.z); au.s[7] = f2bf(x1.w);
      afrag = au.v;
    } else {
      const unsigned short* Ab = (const unsigned short*)Aptr + (size_t)row * K + k0;
      BU au;
      au.u = *(const uint4*)Ab;
      afrag = au.v;
    }
#pragma unroll
    for (int c = 0; c < NCT; ++c)
      acc[c] = __builtin_amdgcn_mfma_f32_16x16x32_bf16(afrag, bfrag[s][c], acc[c], 0, 0, 0);
  }

  // Epilogue: D lane layout col=lane&15, row=quad*4+reg
#pragma unroll
  for (int c = 0; c < NCT; ++c) {
    int colv = g * 48 + c * 16 + lm;
    if (colv >= MVALID) continue;
#pragma unroll
    for (int r = 0; r < 4; ++r) {
      int orow = rt * 16 + quad * 4 + r;
      if (orow < N) {
        if (OUTBF16)
          ((unsigned short*)outp)[(size_t)orow * MOUT + colv] = f2bf(acc[c][r]);
        else
          ((float*)outp)[(size_t)orow * MOUT + colv] = acc[c][r];
      }
    }
  }
}

// ---------------- Aggregation over CSR, bf16 in / bf16 out ----------------
// 12 threads per node, 8 features each (16 B loads). F = 96.

__global__ void agg_relu_bf16(const unsigned short* __restrict__ t,
                              const int* __restrict__ row_ptr, const int* __restrict__ col,
                              const float* __restrict__ bias, unsigned short* __restrict__ out,
                              int N) {
  int gid = blockIdx.x * blockDim.x + threadIdx.x;
  int node = gid / 12;
  int c = gid - node * 12;
  if (node >= N) return;
  int beg = row_ptr[node];
  int end = row_ptr[node + 1];
  const unsigned short* tc = t + 8 * c;
  float a0 = 0.f, a1 = 0.f, a2 = 0.f, a3 = 0.f, a4 = 0.f, a5 = 0.f, a6 = 0.f, a7 = 0.f;
  for (int e = beg; e < end; ++e) {
    int s = col[e];
    uint4 u = *(const uint4*)(tc + (size_t)s * 96);
    a0 += bflo(u.x); a1 += bfhi(u.x);
    a2 += bflo(u.y); a3 += bfhi(u.y);
    a4 += bflo(u.z); a5 += bfhi(u.z);
    a6 += bflo(u.w); a7 += bfhi(u.w);
  }
  const float* b = bias + 8 * c;
  union { unsigned short s[8]; uint4 u; } pk;
  pk.s[0] = f2bf(fmaxf(a0 + b[0], 0.f));
  pk.s[1] = f2bf(fmaxf(a1 + b[1], 0.f));
  pk.s[2] = f2bf(fmaxf(a2 + b[2], 0.f));
  pk.s[3] = f2bf(fmaxf(a3 + b[3], 0.f));
  pk.s[4] = f2bf(fmaxf(a4 + b[4], 0.f));
  pk.s[5] = f2bf(fmaxf(a5 + b[5], 0.f));
  pk.s[6] = f2bf(fmaxf(a6 + b[6], 0.f));
  pk.s[7] = f2bf(fmaxf(a7 + b[7], 0.f));
  *(uint4*)(out + (size_t)node * 96 + 8 * c) = pk.u;
}

// Layer-3 aggregation (f32 in) + bias + log_softmax over 40 classes.
// 16-lane group per node; lanes 0..9 hold float4 chunks.
__global__ void agg_lsm_v4(const float* __restrict__ t, const int* __restrict__ row_ptr,
                           const int* __restrict__ col, const float* __restrict__ bias,
                           float* __restrict__ out, int N) {
  int tid = threadIdx.x;
  int node = blockIdx.x * 16 + (tid >> 4);
  int c = tid & 15;  // 0..9 active
  bool act = (c < 10) && (node < N);
  int ceff = (c < 10) ? c : 0;
  int beg = 0, end = 0;
  if (node < N) {
    beg = row_ptr[node];
    end = row_ptr[node + 1];
  }
  const float* tc = t + 4 * ceff;
  float4 acc = make_float4(0.f, 0.f, 0.f, 0.f);
  if (act) {
    for (int e = beg; e < end; ++e) {
      int s = col[e];
      float4 v = *(const float4*)(tc + (size_t)s * 40);
      acc.x += v.x; acc.y += v.y; acc.z += v.z; acc.w += v.w;
    }
  }
  float4 b = ((const float4*)bias)[ceff];
  float v0 = acc.x + b.x, v1 = acc.y + b.y, v2 = acc.z + b.z, v3 = acc.w + b.w;
  float m = act ? fmaxf(fmaxf(v0, v1), fmaxf(v2, v3)) : -__builtin_inff();
#pragma unroll
  for (int off = 8; off; off >>= 1) m = fmaxf(m, __shfl_xor(m, off, 64));
  float ex = act ? (__expf(v0 - m) + __expf(v1 - m) + __expf(v2 - m) + __expf(v3 - m)) : 0.f;
#pragma unroll
  for (int off = 8; off; off >>= 1) ex += __shfl_xor(ex, off, 64);
  if (act) {
    float l = m + __logf(ex);
    float* o = out + (size_t)node * 40 + 4 * c;
    o[0] = v0 - l; o[1] = v1 - l; o[2] = v2 - l; o[3] = v3 - l;
  }
}

// ---------------- Launch ----------------

extern "C" void kernel_launch(void* const* d_in, const int* in_sizes, int n_in,
                              void* d_out, int out_size, void* d_ws, size_t ws_size,
                              hipStream_t stream) {
  const float* x  = (const float*)d_in[0];   // [N,128]
  const float* W1 = (const float*)d_in[1];   // [128,96]
  const float* b1 = (const float*)d_in[2];   // [96]
  const float* W2 = (const float*)d_in[3];   // [96,96]
  const float* b2 = (const float*)d_in[4];   // [96]
  const float* W3 = (const float*)d_in[5];   // [96,40]
  const float* b3 = (const float*)d_in[6];   // [40]
  const int* edge = (const int*)d_in[7];     // [2,E] int32

  int N = in_sizes[0] / 128;  // 50000
  int E = in_sizes[7] / 2;    // 800000
  const int* srcp = edge;
  const int* dstp = edge + E;

  char* p = (char*)d_ws;
  auto alloc = [&](size_t bytes) {
    char* r = p;
    p += (bytes + 255) & ~size_t(255);
    return r;
  };
  int* counts  = (int*)alloc((size_t)N * 4);
  int* cursor  = (int*)alloc((size_t)N * 4);
  int* row_ptr = (int*)alloc((size_t)(N + 1) * 4);
  int* col     = (int*)alloc((size_t)E * 4);
  int* bsum    = (int*)alloc(256 * 4);
  unsigned short* Wp1 = (unsigned short*)alloc(1536 * 8 * 2);
  unsigned short* Wp2 = (unsigned short*)alloc(1152 * 8 * 2);
  unsigned short* Wp3 = (unsigned short*)alloc(576 * 8 * 2);
  unsigned short* Tb  = (unsigned short*)alloc((size_t)N * 96 * 2);  // bf16 GEMM out
  unsigned short* Hb  = (unsigned short*)alloc((size_t)N * 96 * 2);  // bf16 agg out
  float* T3 = (float*)alloc((size_t)N * 40 * 4);                     // f32 layer-3 pre-agg

  int nsb = (N + SCAN_B - 1) / SCAN_B;

  // CSR build
  zero_kernel<<<(N + 255) / 256, 256, 0, stream>>>(counts, N);
  hist_kernel<<<(E + 255) / 256, 256, 0, stream>>>(dstp, counts, E);
  scan_part1<<<nsb, SCAN_T, 0, stream>>>(counts, bsum, N);
  scan_part2<<<1, 256, 0, stream>>>(bsum, row_ptr, nsb, N);
  scan_part3<<<nsb, SCAN_T, 0, stream>>>(counts, bsum, row_ptr, cursor, N);
  scatter_kernel<<<(E + 255) / 256, 256, 0, stream>>>(srcp, dstp, cursor, col, E);

  // Pack weights to MFMA fragment order
  pack_w_kernel<<<13, 256, 0, stream>>>(W1, W2, W3, Wp1, Wp2, Wp3);

  int rt4 = ((N + 15) / 16 + 3) / 4;  // blocks of 4 row-tiles
  int aggblocks = (N * 12 + 255) / 256;

  // Layer 1: t = bf16(x) @ W1 ; h = relu(agg(t) + b1)
  mfma_gemm<4, 6, true, true, 96, 96><<<dim3(rt4, 2), 256, 0, stream>>>(x, Wp1, Tb, N);
  agg_relu_bf16<<<aggblocks, 256, 0, stream>>>(Tb, row_ptr, col, b1, Hb, N);
  // Layer 2
  mfma_gemm<3, 6, false, true, 96, 96><<<dim3(rt4, 2), 256, 0, stream>>>(Hb, Wp2, Tb, N);
  agg_relu_bf16<<<aggblocks, 256, 0, stream>>>(Tb, row_ptr, col, b2, Hb, N);
  // Layer 3 + log_softmax
  mfma_gemm<3, 3, false, false, 40, 40><<<dim3(rt4, 1), 256, 0, stream>>>(Hb, Wp3, T3, N);
  agg_lsm_v4<<<(N + 15) / 16, 256, 0, stream>>>(T3, row_ptr, col, b3, (float*)d_out, N);
}

// Round 4
// 256.985 us; speedup vs baseline: 2.3574x; 1.2182x over previous
//
#include <hip/hip_runtime.h>
#include <math.h>

typedef __attribute__((ext_vector_type(8))) short bf16x8;
typedef __attribute__((ext_vector_type(4))) float f32x4;

__device__ __forceinline__ unsigned short f2bf(float f) {
  unsigned u = __float_as_uint(f);
  u += 0x7fffu + ((u >> 16) & 1u);  // round-to-nearest-even
  return (unsigned short)(u >> 16);
}
__device__ __forceinline__ float bflo(unsigned u) { return __uint_as_float(u << 16); }
__device__ __forceinline__ float bfhi(unsigned u) { return __uint_as_float(u & 0xffff0000u); }

// ================= CSR via two-level bucket binning =================
// Buckets of 1024 nodes (NB = ceil(N/1024)). packed edge = (d_local<<16)|src.
// Requires N <= 65536 (src fits 16 bits) — N = 50000 here.

__global__ __launch_bounds__(256) void bucket_count(const int* __restrict__ dst,
                                                    int* __restrict__ rtot, int E, int NB) {
  __shared__ int bkt[64];
  int tid = threadIdx.x;
  if (tid < 64) bkt[tid] = 0;
  __syncthreads();
  int E4 = E >> 2;
  const int4* d4 = (const int4*)dst;
  for (int i = blockIdx.x * 256 + tid; i < E4; i += gridDim.x * 256) {
    int4 d = d4[i];
    atomicAdd(&bkt[d.x >> 10], 1);
    atomicAdd(&bkt[d.y >> 10], 1);
    atomicAdd(&bkt[d.z >> 10], 1);
    atomicAdd(&bkt[d.w >> 10], 1);
  }
  if (blockIdx.x == 0 && tid < (E & 3)) atomicAdd(&bkt[dst[E4 * 4 + tid] >> 10], 1);
  __syncthreads();
  if (tid < NB) atomicAdd(&rtot[tid], bkt[tid]);
}

// One wave: exclusive scan of NB (<=64) bucket totals.
__global__ void scan_small(const int* __restrict__ rtot, int* __restrict__ gstart,
                           int* __restrict__ gcur, int* __restrict__ row_ptr,
                           int NB, int N, int E) {
  int t = threadIdx.x;
  int v = (t < NB) ? rtot[t] : 0;
  int orig = v;
#pragma unroll
  for (int off = 1; off < 64; off <<= 1) {
    int u = __shfl_up(v, off, 64);
    if (t >= off) v += u;
  }
  int excl = v - orig;
  if (t < NB) { gstart[t] = excl; gcur[t] = excl; }
  if (t == NB - 1) gstart[NB] = v;
  if (t == 0) row_ptr[N] = E;
}

// Bin edges into bucket-contiguous packed array.
__global__ __launch_bounds__(512) void bin_edges(const int* __restrict__ src,
                                                 const int* __restrict__ dst,
                                                 int* __restrict__ gcur,
                                                 int* __restrict__ packed, int E, int NB) {
  __shared__ int lcnt[64];
  __shared__ int gbase[64];
  int tid = threadIdx.x;
  if (tid < 64) lcnt[tid] = 0;
  __syncthreads();
  int idx = blockIdx.x * 512 + tid;  // int4 index
  int E4 = E >> 2;
  int sv[4], dv[4], lv[4];
  int cnt = 0;
  if (idx < E4) {
    int4 s4 = ((const int4*)src)[idx];
    int4 d4 = ((const int4*)dst)[idx];
    sv[0] = s4.x; sv[1] = s4.y; sv[2] = s4.z; sv[3] = s4.w;
    dv[0] = d4.x; dv[1] = d4.y; dv[2] = d4.z; dv[3] = d4.w;
    cnt = 4;
  } else if (idx == E4 && (E & 3)) {
    int tl = E & 3;
    for (int i = 0; i < tl; ++i) { sv[i] = src[E4 * 4 + i]; dv[i] = dst[E4 * 4 + i]; }
    cnt = tl;
  }
  for (int i = 0; i < cnt; ++i) lv[i] = atomicAdd(&lcnt[dv[i] >> 10], 1);
  __syncthreads();
  if (tid < NB) gbase[tid] = atomicAdd(&gcur[tid], lcnt[tid]);
  __syncthreads();
  for (int i = 0; i < cnt; ++i) {
    int b = dv[i] >> 10;
    packed[gbase[b] + lv[i]] = ((dv[i] & 1023) << 16) | (sv[i] & 0xffff);
  }
}

// One block per bucket: local count -> local scan -> row_ptr + col.
__global__ __launch_bounds__(1024) void build_local_csr(const int* __restrict__ packed,
                                                        const int* __restrict__ gstart,
                                                        int* __restrict__ row_ptr,
                                                        int* __restrict__ col, int N) {
  __shared__ int cnt[1024];
  __shared__ int sm[1024];
  int b = blockIdx.x, tid = threadIdx.x;
  int gs = gstart[b], ge = gstart[b + 1];
  int me = ge - gs;
  int node0 = b << 10;
  int RL = N - node0;
  if (RL > 1024) RL = 1024;
  cnt[tid] = 0;
  __syncthreads();
  for (int i = tid; i < me; i += 1024) atomicAdd(&cnt[packed[gs + i] >> 16], 1);
  __syncthreads();
  int v = cnt[tid];
  sm[tid] = v;
  __syncthreads();
  for (int off = 1; off < 1024; off <<= 1) {
    int u = (tid >= off) ? sm[tid - off] : 0;
    __syncthreads();
    sm[tid] += u;
    __syncthreads();
  }
  int excl = gs + sm[tid] - v;
  __syncthreads();
  cnt[tid] = excl;  // repurpose as cursor
  if (tid < RL) row_ptr[node0 + tid] = excl;
  __syncthreads();
  for (int i = tid; i < me; i += 1024) {
    int pk = packed[gs + i];
    int d = pk >> 16;
    int p = atomicAdd(&cnt[d], 1);
    col[p] = pk & 0xffff;
  }
}

// ================= W pre-pack into MFMA B-fragment order (bf16) =================

__global__ void pack_w_kernel(const float* __restrict__ W1, const float* __restrict__ W2,
                              const float* __restrict__ W3, unsigned short* __restrict__ Wp1,
                              unsigned short* __restrict__ Wp2, unsigned short* __restrict__ Wp3) {
  int gid = blockIdx.x * blockDim.x + threadIdx.x;
  const float* W;
  unsigned short* Wp;
  int t, NCTT, M, MV;
  if (gid < 1536) {            // W1: 4 ksteps * 6 coltiles * 64 lanes
    W = W1; Wp = Wp1; t = gid; NCTT = 6; M = 96; MV = 96;
  } else if (gid < 2688) {     // W2: 3 * 6 * 64
    W = W2; Wp = Wp2; t = gid - 1536; NCTT = 6; M = 96; MV = 96;
  } else if (gid < 3264) {     // W3: 3 * 3 * 64 (padded to 48 cols)
    W = W3; Wp = Wp3; t = gid - 2688; NCTT = 3; M = 40; MV = 40;
  } else {
    return;
  }
  int lane = t & 63;
  int frag = t >> 6;
  int s = frag / NCTT;
  int ct = frag - s * NCTT;
  int colv = ct * 16 + (lane & 15);
  int k0 = s * 32 + (lane >> 4) * 8;
  union { unsigned short s[8]; uint4 u; } pk;
#pragma unroll
  for (int j = 0; j < 8; ++j) {
    float v = (colv < MV) ? W[(k0 + j) * M + colv] : 0.f;
    pk.s[j] = f2bf(v);
  }
  ((uint4*)Wp)[t] = pk.u;
}

// ================= MFMA GEMM =================

template <int KSTEPS, int NCTT, bool AF32, bool OUTBF16, int MOUT, int MVALID>
__global__ __launch_bounds__(256) void mfma_gemm(const void* __restrict__ Aptr,
                                                 const unsigned short* __restrict__ Wp,
                                                 void* __restrict__ outp, int N) {
  constexpr int NCT = 3;
  constexpr int K = KSTEPS * 32;
  int wid = threadIdx.x >> 6;
  int lane = threadIdx.x & 63;
  int rt = blockIdx.x * 4 + wid;
  if (rt * 16 >= N) return;
  int g = blockIdx.y;
  int quad = lane >> 4;
  int lm = lane & 15;

  union BU { uint4 u; bf16x8 v; };
  bf16x8 bfrag[KSTEPS][NCT];
  const uint4* wp4 = (const uint4*)Wp;
#pragma unroll
  for (int s = 0; s < KSTEPS; ++s)
#pragma unroll
    for (int c = 0; c < NCT; ++c) {
      BU bu;
      bu.u = wp4[(s * NCTT + g * NCT + c) * 64 + lane];
      bfrag[s][c] = bu.v;
    }

  f32x4 acc[NCT];
#pragma unroll
  for (int c = 0; c < NCT; ++c) acc[c] = (f32x4){0.f, 0.f, 0.f, 0.f};

  int row = rt * 16 + lm;
  if (row >= N) row = N - 1;

#pragma unroll
  for (int s = 0; s < KSTEPS; ++s) {
    int k0 = s * 32 + quad * 8;
    bf16x8 afrag;
    if (AF32) {
      const float* Af = (const float*)Aptr + (size_t)row * K + k0;
      float4 x0 = *(const float4*)(Af);
      float4 x1 = *(const float4*)(Af + 4);
      union { unsigned short s[8]; bf16x8 v; } au;
      au.s[0] = f2bf(x0.x); au.s[1] = f2bf(x0.y); au.s[2] = f2bf(x0.z); au.s[3] = f2bf(x0.w);
      au.s[4] = f2bf(x1.x); au.s[5] = f2bf(x1.y); au.s[6] = f2bf(x1.z); au.s[7] = f2bf(x1.w);
      afrag = au.v;
    } else {
      const unsigned short* Ab = (const unsigned short*)Aptr + (size_t)row * K + k0;
      BU au;
      au.u = *(const uint4*)Ab;
      afrag = au.v;
    }
#pragma unroll
    for (int c = 0; c < NCT; ++c)
      acc[c] = __builtin_amdgcn_mfma_f32_16x16x32_bf16(afrag, bfrag[s][c], acc[c], 0, 0, 0);
  }

#pragma unroll
  for (int c = 0; c < NCT; ++c) {
    int colv = g * 48 + c * 16 + lm;
    if (colv >= MVALID) continue;
#pragma unroll
    for (int r = 0; r < 4; ++r) {
      int orow = rt * 16 + quad * 4 + r;
      if (orow < N) {
        if (OUTBF16)
          ((unsigned short*)outp)[(size_t)orow * MOUT + colv] = f2bf(acc[c][r]);
        else
          ((float*)outp)[(size_t)orow * MOUT + colv] = acc[c][r];
      }
    }
  }
}

// ================= Aggregation =================
// 12 threads per node, 8 bf16 features each (16 B loads). F = 96.

__global__ void agg_relu_bf16(const unsigned short* __restrict__ t,
                              const int* __restrict__ row_ptr, const int* __restrict__ col,
                              const float* __restrict__ bias, unsigned short* __restrict__ out,
                              int N) {
  int gid = blockIdx.x * blockDim.x + threadIdx.x;
  int node = gid / 12;
  int c = gid - node * 12;
  if (node >= N) return;
  int beg = row_ptr[node];
  int end = row_ptr[node + 1];
  const unsigned short* tc = t + 8 * c;
  float a0 = 0.f, a1 = 0.f, a2 = 0.f, a3 = 0.f, a4 = 0.f, a5 = 0.f, a6 = 0.f, a7 = 0.f;
  for (int e = beg; e < end; ++e) {
    int s = col[e];
    uint4 u = *(const uint4*)(tc + (size_t)s * 96);
    a0 += bflo(u.x); a1 += bfhi(u.x);
    a2 += bflo(u.y); a3 += bfhi(u.y);
    a4 += bflo(u.z); a5 += bfhi(u.z);
    a6 += bflo(u.w); a7 += bfhi(u.w);
  }
  const float* b = bias + 8 * c;
  union { unsigned short s[8]; uint4 u; } pk;
  pk.s[0] = f2bf(fmaxf(a0 + b[0], 0.f));
  pk.s[1] = f2bf(fmaxf(a1 + b[1], 0.f));
  pk.s[2] = f2bf(fmaxf(a2 + b[2], 0.f));
  pk.s[3] = f2bf(fmaxf(a3 + b[3], 0.f));
  pk.s[4] = f2bf(fmaxf(a4 + b[4], 0.f));
  pk.s[5] = f2bf(fmaxf(a5 + b[5], 0.f));
  pk.s[6] = f2bf(fmaxf(a6 + b[6], 0.f));
  pk.s[7] = f2bf(fmaxf(a7 + b[7], 0.f));
  *(uint4*)(out + (size_t)node * 96 + 8 * c) = pk.u;
}

// Layer-3 aggregation (bf16 in) + bias + log_softmax over 40 classes.
// 16-lane group per node; lanes 0..9 each hold 4 classes (uint2 = 4 bf16).
__global__ void agg_lsm_bf16(const unsigned short* __restrict__ t,
                             const int* __restrict__ row_ptr, const int* __restrict__ col,
                             const float* __restrict__ bias, float* __restrict__ out, int N) {
  int tid = threadIdx.x;
  int node = blockIdx.x * 16 + (tid >> 4);
  int c = tid & 15;  // 0..9 active
  bool act = (c < 10) && (node < N);
  int ceff = (c < 10) ? c : 0;
  int beg = 0, end = 0;
  if (node < N) {
    beg = row_ptr[node];
    end = row_ptr[node + 1];
  }
  const unsigned short* tc = t + 4 * ceff;
  float v0 = 0.f, v1 = 0.f, v2 = 0.f, v3 = 0.f;
  if (act) {
    for (int e = beg; e < end; ++e) {
      int s = col[e];
      uint2 u = *(const uint2*)(tc + (size_t)s * 40);
      v0 += bflo(u.x); v1 += bfhi(u.x);
      v2 += bflo(u.y); v3 += bfhi(u.y);
    }
  }
  const float* bb = bias + 4 * ceff;
  v0 += bb[0]; v1 += bb[1]; v2 += bb[2]; v3 += bb[3];
  float m = act ? fmaxf(fmaxf(v0, v1), fmaxf(v2, v3)) : -__builtin_inff();
#pragma unroll
  for (int off = 8; off; off >>= 1) m = fmaxf(m, __shfl_xor(m, off, 64));
  float ex = act ? (__expf(v0 - m) + __expf(v1 - m) + __expf(v2 - m) + __expf(v3 - m)) : 0.f;
#pragma unroll
  for (int off = 8; off; off >>= 1) ex += __shfl_xor(ex, off, 64);
  if (act) {
    float l = m + __logf(ex);
    float* o = out + (size_t)node * 40 + 4 * c;
    o[0] = v0 - l; o[1] = v1 - l; o[2] = v2 - l; o[3] = v3 - l;
  }
}

// ================= Launch =================

extern "C" void kernel_launch(void* const* d_in, const int* in_sizes, int n_in,
                              void* d_out, int out_size, void* d_ws, size_t ws_size,
                              hipStream_t stream) {
  const float* x  = (const float*)d_in[0];
  const float* W1 = (const float*)d_in[1];
  const float* b1 = (const float*)d_in[2];
  const float* W2 = (const float*)d_in[3];
  const float* b2 = (const float*)d_in[4];
  const float* W3 = (const float*)d_in[5];
  const float* b3 = (const float*)d_in[6];
  const int* edge = (const int*)d_in[7];

  int N = in_sizes[0] / 128;  // 50000
  int E = in_sizes[7] / 2;    // 800000
  const int* srcp = edge;
  const int* dstp = edge + E;

  char* p = (char*)d_ws;
  auto alloc = [&](size_t bytes) {
    char* r = p;
    p += (bytes + 255) & ~size_t(255);
    return r;
  };
  int NB = (N + 1023) >> 10;  // 49 buckets
  int* rtot    = (int*)alloc((size_t)NB * 4);
  int* gstart  = (int*)alloc((size_t)(NB + 1) * 4);
  int* gcur    = (int*)alloc((size_t)NB * 4);
  int* row_ptr = (int*)alloc((size_t)(N + 1) * 4);
  int* packed  = (int*)alloc((size_t)E * 4);
  int* col     = (int*)alloc((size_t)E * 4);
  unsigned short* Wp1 = (unsigned short*)alloc(1536 * 8 * 2);
  unsigned short* Wp2 = (unsigned short*)alloc(1152 * 8 * 2);
  unsigned short* Wp3 = (unsigned short*)alloc(576 * 8 * 2);
  unsigned short* Tb  = (unsigned short*)alloc((size_t)N * 96 * 2);
  unsigned short* Hb  = (unsigned short*)alloc((size_t)N * 96 * 2);
  unsigned short* T3b = (unsigned short*)alloc((size_t)N * 40 * 2);

  // --- CSR build via bucket binning ---
  hipMemsetAsync(rtot, 0, (size_t)NB * 4, stream);
  bucket_count<<<512, 256, 0, stream>>>(dstp, rtot, E, NB);
  scan_small<<<1, 64, 0, stream>>>(rtot, gstart, gcur, row_ptr, NB, N, E);
  int E4 = E >> 2;
  int nbin = (E4 + ((E & 3) ? 1 : 0) + 511) / 512;
  bin_edges<<<nbin, 512, 0, stream>>>(srcp, dstp, gcur, packed, E, NB);
  build_local_csr<<<NB, 1024, 0, stream>>>(packed, gstart, row_ptr, col, N);

  // --- Weights to MFMA fragment order ---
  pack_w_kernel<<<13, 256, 0, stream>>>(W1, W2, W3, Wp1, Wp2, Wp3);

  int rt4 = ((N + 15) / 16 + 3) / 4;
  int aggblocks = (N * 12 + 255) / 256;

  // Layer 1
  mfma_gemm<4, 6, true, true, 96, 96><<<dim3(rt4, 2), 256, 0, stream>>>(x, Wp1, Tb, N);
  agg_relu_bf16<<<aggblocks, 256, 0, stream>>>(Tb, row_ptr, col, b1, Hb, N);
  // Layer 2
  mfma_gemm<3, 6, false, true, 96, 96><<<dim3(rt4, 2), 256, 0, stream>>>(Hb, Wp2, Tb, N);
  agg_relu_bf16<<<aggblocks, 256, 0, stream>>>(Tb, row_ptr, col, b2, Hb, N);
  // Layer 3 + log_softmax
  mfma_gemm<3, 3, false, true, 40, 40><<<dim3(rt4, 1), 256, 0, stream>>>(Hb, Wp3, T3b, N);
  agg_lsm_bf16<<<(N + 15) / 16, 256, 0, stream>>>(T3b, row_ptr, col, b3, (float*)d_out, N);
}

// Round 5
// 219.628 us; speedup vs baseline: 2.7583x; 1.1701x over previous
//
#include <hip/hip_runtime.h>
#include <math.h>

typedef __attribute__((ext_vector_type(8))) short bf16x8;
typedef __attribute__((ext_vector_type(4))) float f32x4;

__device__ __forceinline__ unsigned short f2bf(float f) {
  unsigned u = __float_as_uint(f);
  u += 0x7fffu + ((u >> 16) & 1u);  // round-to-nearest-even
  return (unsigned short)(u >> 16);
}
__device__ __forceinline__ float bflo(unsigned u) { return __uint_as_float(u << 16); }
__device__ __forceinline__ float bfhi(unsigned u) { return __uint_as_float(u & 0xffff0000u); }

// ================= CSR via two-level bucket binning =================
// Buckets of 256 nodes (NB = ceil(N/256) = 196). packed edge = (d_local<<16)|src.
// Requires N <= 65536 (src fits 16 bits) — N = 50000 here.

constexpr int CB = 64;  // bucket_count blocks

// Per-block partial histograms (no global atomics, no memset needed).
__global__ __launch_bounds__(256) void bucket_count(const int* __restrict__ dst,
                                                    int* __restrict__ partial, int E) {
  __shared__ int bkt[256];
  int tid = threadIdx.x;
  bkt[tid] = 0;
  __syncthreads();
  int E4 = E >> 2;
  const int4* d4 = (const int4*)dst;
  for (int i = blockIdx.x * 256 + tid; i < E4; i += gridDim.x * 256) {
    int4 d = d4[i];
    atomicAdd(&bkt[d.x >> 8], 1);
    atomicAdd(&bkt[d.y >> 8], 1);
    atomicAdd(&bkt[d.z >> 8], 1);
    atomicAdd(&bkt[d.w >> 8], 1);
  }
  if (blockIdx.x == 0 && tid < (E & 3)) atomicAdd(&bkt[dst[E4 * 4 + tid] >> 8], 1);
  __syncthreads();
  partial[blockIdx.x * 256 + tid] = bkt[tid];
}

// Block 0: reduce partials + exclusive scan -> gstart/gcur. Blocks 1..13: pack W
// into MFMA B-fragment order. Fragment (s,ct): lane l holds
// B[k=s*32+(l>>4)*8+j][col=ct*16+(l&15)], j=0..7, 8 contiguous bf16.
__global__ __launch_bounds__(256) void scan_pack(const int* __restrict__ partial,
                                                 int* __restrict__ gstart, int* __restrict__ gcur,
                                                 int* __restrict__ row_ptr,
                                                 const float* __restrict__ W1,
                                                 const float* __restrict__ W2,
                                                 const float* __restrict__ W3,
                                                 unsigned short* __restrict__ Wp1,
                                                 unsigned short* __restrict__ Wp2,
                                                 unsigned short* __restrict__ Wp3,
                                                 int NB, int N, int E) {
  if (blockIdx.x == 0) {
    int tid = threadIdx.x;
    int s = 0;
#pragma unroll 8
    for (int i = 0; i < CB; ++i) s += partial[i * 256 + tid];  // buckets >= NB are 0
    __shared__ int sm[256];
    sm[tid] = s;
    __syncthreads();
    for (int off = 1; off < 256; off <<= 1) {
      int u = (tid >= off) ? sm[tid - off] : 0;
      __syncthreads();
      sm[tid] += u;
      __syncthreads();
    }
    int excl = sm[tid] - s;
    if (tid < NB) { gstart[tid] = excl; gcur[tid] = excl; }
    if (tid == NB - 1) gstart[NB] = sm[tid];
    if (tid == 0) row_ptr[N] = E;
    return;
  }
  int gid = (blockIdx.x - 1) * 256 + threadIdx.x;
  const float* W;
  unsigned short* Wp;
  int t, NCTT, M, MV;
  if (gid < 1536) {            // W1: 4 ksteps * 6 coltiles * 64 lanes
    W = W1; Wp = Wp1; t = gid; NCTT = 6; M = 96; MV = 96;
  } else if (gid < 2688) {     // W2: 3 * 6 * 64
    W = W2; Wp = Wp2; t = gid - 1536; NCTT = 6; M = 96; MV = 96;
  } else if (gid < 3264) {     // W3: 3 * 3 * 64 (cols >= 40 zero-padded)
    W = W3; Wp = Wp3; t = gid - 2688; NCTT = 3; M = 40; MV = 40;
  } else {
    return;
  }
  int lane = t & 63;
  int frag = t >> 6;
  int s = frag / NCTT;
  int ct = frag - s * NCTT;
  int colv = ct * 16 + (lane & 15);
  int k0 = s * 32 + (lane >> 4) * 8;
  union { unsigned short s[8]; uint4 u; } pk;
#pragma unroll
  for (int j = 0; j < 8; ++j) {
    float v = (colv < MV) ? W[(k0 + j) * M + colv] : 0.f;
    pk.s[j] = f2bf(v);
  }
  ((uint4*)Wp)[t] = pk.u;
}

// Bin edges into bucket-contiguous packed array.
__global__ __launch_bounds__(512) void bin_edges(const int* __restrict__ src,
                                                 const int* __restrict__ dst,
                                                 int* __restrict__ gcur,
                                                 int* __restrict__ packed, int E, int NB) {
  __shared__ int lcnt[256];
  __shared__ int gbase[256];
  int tid = threadIdx.x;
  if (tid < 256) lcnt[tid] = 0;
  __syncthreads();
  int idx = blockIdx.x * 512 + tid;  // int4 index
  int E4 = E >> 2;
  int sv[4], dv[4], lv[4];
  int cnt = 0;
  if (idx < E4) {
    int4 s4 = ((const int4*)src)[idx];
    int4 d4 = ((const int4*)dst)[idx];
    sv[0] = s4.x; sv[1] = s4.y; sv[2] = s4.z; sv[3] = s4.w;
    dv[0] = d4.x; dv[1] = d4.y; dv[2] = d4.z; dv[3] = d4.w;
    cnt = 4;
  } else if (idx == E4 && (E & 3)) {
    int tl = E & 3;
    for (int i = 0; i < tl; ++i) { sv[i] = src[E4 * 4 + i]; dv[i] = dst[E4 * 4 + i]; }
    cnt = tl;
  }
  for (int i = 0; i < cnt; ++i) lv[i] = atomicAdd(&lcnt[dv[i] >> 8], 1);
  __syncthreads();
  if (tid < NB) gbase[tid] = atomicAdd(&gcur[tid], lcnt[tid]);
  __syncthreads();
  for (int i = 0; i < cnt; ++i) {
    int b = dv[i] >> 8;
    packed[gbase[b] + lv[i]] = ((dv[i] & 255) << 16) | (sv[i] & 0xffff);
  }
}

// One block per 256-node bucket: local count -> local scan -> row_ptr + col.
__global__ __launch_bounds__(256) void build_local_csr(const int* __restrict__ packed,
                                                       const int* __restrict__ gstart,
                                                       int* __restrict__ row_ptr,
                                                       int* __restrict__ col, int N) {
  __shared__ int cnt[256];
  __shared__ int sm[256];
  int b = blockIdx.x, tid = threadIdx.x;
  int gs = gstart[b], ge = gstart[b + 1];
  int me = ge - gs;
  int node0 = b << 8;
  int RL = N - node0;
  if (RL > 256) RL = 256;
  cnt[tid] = 0;
  __syncthreads();
  for (int i = tid; i < me; i += 256) atomicAdd(&cnt[packed[gs + i] >> 16], 1);
  __syncthreads();
  int v = cnt[tid];
  sm[tid] = v;
  __syncthreads();
  for (int off = 1; off < 256; off <<= 1) {
    int u = (tid >= off) ? sm[tid - off] : 0;
    __syncthreads();
    sm[tid] += u;
    __syncthreads();
  }
  int excl = gs + sm[tid] - v;
  __syncthreads();
  cnt[tid] = excl;  // repurpose as cursor
  if (tid < RL) row_ptr[node0 + tid] = excl;
  __syncthreads();
  for (int i = tid; i < me; i += 256) {
    int pk = packed[gs + i];
    int p = atomicAdd(&cnt[pk >> 16], 1);
    col[p] = pk & 0xffff;
  }
}

// ================= MFMA GEMM =================

template <int KSTEPS, int NCTT, bool AF32, bool OUTBF16, int MOUT, int MVALID>
__global__ __launch_bounds__(256) void mfma_gemm(const void* __restrict__ Aptr,
                                                 const unsigned short* __restrict__ Wp,
                                                 void* __restrict__ outp, int N) {
  constexpr int NCT = 3;
  constexpr int K = KSTEPS * 32;
  int wid = threadIdx.x >> 6;
  int lane = threadIdx.x & 63;
  int rt = blockIdx.x * 4 + wid;
  if (rt * 16 >= N) return;
  int g = blockIdx.y;
  int quad = lane >> 4;
  int lm = lane & 15;

  union BU { uint4 u; bf16x8 v; };
  bf16x8 bfrag[KSTEPS][NCT];
  const uint4* wp4 = (const uint4*)Wp;
#pragma unroll
  for (int s = 0; s < KSTEPS; ++s)
#pragma unroll
    for (int c = 0; c < NCT; ++c) {
      BU bu;
      bu.u = wp4[(s * NCTT + g * NCT + c) * 64 + lane];
      bfrag[s][c] = bu.v;
    }

  f32x4 acc[NCT];
#pragma unroll
  for (int c = 0; c < NCT; ++c) acc[c] = (f32x4){0.f, 0.f, 0.f, 0.f};

  int row = rt * 16 + lm;
  if (row >= N) row = N - 1;

#pragma unroll
  for (int s = 0; s < KSTEPS; ++s) {
    int k0 = s * 32 + quad * 8;
    bf16x8 afrag;
    if (AF32) {
      const float* Af = (const float*)Aptr + (size_t)row * K + k0;
      float4 x0 = *(const float4*)(Af);
      float4 x1 = *(const float4*)(Af + 4);
      union { unsigned short s[8]; bf16x8 v; } au;
      au.s[0] = f2bf(x0.x); au.s[1] = f2bf(x0.y); au.s[2] = f2bf(x0.z); au.s[3] = f2bf(x0.w);
      au.s[4] = f2bf(x1.x); au.s[5] = f2bf(x1.y); au.s[6] = f2bf(x1.z); au.s[7] = f2bf(x1.w);
      afrag = au.v;
    } else {
      const unsigned short* Ab = (const unsigned short*)Aptr + (size_t)row * K + k0;
      BU au;
      au.u = *(const uint4*)Ab;
      afrag = au.v;
    }
#pragma unroll
    for (int c = 0; c < NCT; ++c)
      acc[c] = __builtin_amdgcn_mfma_f32_16x16x32_bf16(afrag, bfrag[s][c], acc[c], 0, 0, 0);
  }

#pragma unroll
  for (int c = 0; c < NCT; ++c) {
    int colv = g * 48 + c * 16 + lm;
    if (colv >= MVALID) continue;
#pragma unroll
    for (int r = 0; r < 4; ++r) {
      int orow = rt * 16 + quad * 4 + r;
      if (orow < N) {
        if (OUTBF16)
          ((unsigned short*)outp)[(size_t)orow * MOUT + colv] = f2bf(acc[c][r]);
        else
          ((float*)outp)[(size_t)orow * MOUT + colv] = acc[c][r];
      }
    }
  }
}

// ================= Aggregation =================
// 12 threads per node, 8 bf16 features each (16 B loads). F = 96. Edge loop
// unrolled x2 for more outstanding gathers.

__global__ void agg_relu_bf16(const unsigned short* __restrict__ t,
                              const int* __restrict__ row_ptr, const int* __restrict__ col,
                              const float* __restrict__ bias, unsigned short* __restrict__ out,
                              int N) {
  int gid = blockIdx.x * blockDim.x + threadIdx.x;
  int node = gid / 12;
  int c = gid - node * 12;
  if (node >= N) return;
  int beg = row_ptr[node];
  int end = row_ptr[node + 1];
  const unsigned short* tc = t + 8 * c;
  float a0 = 0.f, a1 = 0.f, a2 = 0.f, a3 = 0.f, a4 = 0.f, a5 = 0.f, a6 = 0.f, a7 = 0.f;
  int e = beg;
  for (; e + 1 < end; e += 2) {
    int s0 = col[e], s1 = col[e + 1];
    uint4 u = *(const uint4*)(tc + (size_t)s0 * 96);
    uint4 w = *(const uint4*)(tc + (size_t)s1 * 96);
    a0 += bflo(u.x); a1 += bfhi(u.x);
    a2 += bflo(u.y); a3 += bfhi(u.y);
    a4 += bflo(u.z); a5 += bfhi(u.z);
    a6 += bflo(u.w); a7 += bfhi(u.w);
    a0 += bflo(w.x); a1 += bfhi(w.x);
    a2 += bflo(w.y); a3 += bfhi(w.y);
    a4 += bflo(w.z); a5 += bfhi(w.z);
    a6 += bflo(w.w); a7 += bfhi(w.w);
  }
  if (e < end) {
    int s = col[e];
    uint4 u = *(const uint4*)(tc + (size_t)s * 96);
    a0 += bflo(u.x); a1 += bfhi(u.x);
    a2 += bflo(u.y); a3 += bfhi(u.y);
    a4 += bflo(u.z); a5 += bfhi(u.z);
    a6 += bflo(u.w); a7 += bfhi(u.w);
  }
  const float* b = bias + 8 * c;
  union { unsigned short s[8]; uint4 u; } pk;
  pk.s[0] = f2bf(fmaxf(a0 + b[0], 0.f));
  pk.s[1] = f2bf(fmaxf(a1 + b[1], 0.f));
  pk.s[2] = f2bf(fmaxf(a2 + b[2], 0.f));
  pk.s[3] = f2bf(fmaxf(a3 + b[3], 0.f));
  pk.s[4] = f2bf(fmaxf(a4 + b[4], 0.f));
  pk.s[5] = f2bf(fmaxf(a5 + b[5], 0.f));
  pk.s[6] = f2bf(fmaxf(a6 + b[6], 0.f));
  pk.s[7] = f2bf(fmaxf(a7 + b[7], 0.f));
  *(uint4*)(out + (size_t)node * 96 + 8 * c) = pk.u;
}

// Layer-3 aggregation (bf16 in) + bias + log_softmax over 40 classes.
// 16-lane group per node; lanes 0..9 each hold 4 classes (uint2 = 4 bf16).
__global__ void agg_lsm_bf16(const unsigned short* __restrict__ t,
                             const int* __restrict__ row_ptr, const int* __restrict__ col,
                             const float* __restrict__ bias, float* __restrict__ out, int N) {
  int tid = threadIdx.x;
  int node = blockIdx.x * 16 + (tid >> 4);
  int c = tid & 15;  // 0..9 active
  bool act = (c < 10) && (node < N);
  int ceff = (c < 10) ? c : 0;
  int beg = 0, end = 0;
  if (node < N) {
    beg = row_ptr[node];
    end = row_ptr[node + 1];
  }
  const unsigned short* tc = t + 4 * ceff;
  float v0 = 0.f, v1 = 0.f, v2 = 0.f, v3 = 0.f;
  if (act) {
    int e = beg;
    for (; e + 1 < end; e += 2) {
      int s0 = col[e], s1 = col[e + 1];
      uint2 u = *(const uint2*)(tc + (size_t)s0 * 40);
      uint2 w = *(const uint2*)(tc + (size_t)s1 * 40);
      v0 += bflo(u.x); v1 += bfhi(u.x);
      v2 += bflo(u.y); v3 += bfhi(u.y);
      v0 += bflo(w.x); v1 += bfhi(w.x);
      v2 += bflo(w.y); v3 += bfhi(w.y);
    }
    if (e < end) {
      int s = col[e];
      uint2 u = *(const uint2*)(tc + (size_t)s * 40);
      v0 += bflo(u.x); v1 += bfhi(u.x);
      v2 += bflo(u.y); v3 += bfhi(u.y);
    }
  }
  const float* bb = bias + 4 * ceff;
  v0 += bb[0]; v1 += bb[1]; v2 += bb[2]; v3 += bb[3];
  float m = act ? fmaxf(fmaxf(v0, v1), fmaxf(v2, v3)) : -__builtin_inff();
#pragma unroll
  for (int off = 8; off; off >>= 1) m = fmaxf(m, __shfl_xor(m, off, 64));
  float ex = act ? (__expf(v0 - m) + __expf(v1 - m) + __expf(v2 - m) + __expf(v3 - m)) : 0.f;
#pragma unroll
  for (int off = 8; off; off >>= 1) ex += __shfl_xor(ex, off, 64);
  if (act) {
    float l = m + __logf(ex);
    float* o = out + (size_t)node * 40 + 4 * c;
    o[0] = v0 - l; o[1] = v1 - l; o[2] = v2 - l; o[3] = v3 - l;
  }
}

// ================= Launch =================

extern "C" void kernel_launch(void* const* d_in, const int* in_sizes, int n_in,
                              void* d_out, int out_size, void* d_ws, size_t ws_size,
                              hipStream_t stream) {
  const float* x  = (const float*)d_in[0];
  const float* W1 = (const float*)d_in[1];
  const float* b1 = (const float*)d_in[2];
  const float* W2 = (const float*)d_in[3];
  const float* b2 = (const float*)d_in[4];
  const float* W3 = (const float*)d_in[5];
  const float* b3 = (const float*)d_in[6];
  const int* edge = (const int*)d_in[7];

  int N = in_sizes[0] / 128;  // 50000
  int E = in_sizes[7] / 2;    // 800000
  const int* srcp = edge;
  const int* dstp = edge + E;

  char* p = (char*)d_ws;
  auto alloc = [&](size_t bytes) {
    char* r = p;
    p += (bytes + 255) & ~size_t(255);
    return r;
  };
  int NB = (N + 255) >> 8;  // 196 buckets of 256 nodes
  int* partial = (int*)alloc((size_t)CB * 256 * 4);
  int* gstart  = (int*)alloc((size_t)(NB + 1) * 4);
  int* gcur    = (int*)alloc((size_t)NB * 4);
  int* row_ptr = (int*)alloc((size_t)(N + 1) * 4);
  int* packed  = (int*)alloc((size_t)E * 4);
  int* col     = (int*)alloc((size_t)E * 4);
  unsigned short* Wp1 = (unsigned short*)alloc(1536 * 8 * 2);
  unsigned short* Wp2 = (unsigned short*)alloc(1152 * 8 * 2);
  unsigned short* Wp3 = (unsigned short*)alloc(576 * 8 * 2);
  unsigned short* Tb  = (unsigned short*)alloc((size_t)N * 96 * 2);
  unsigned short* Hb  = (unsigned short*)alloc((size_t)N * 96 * 2);
  unsigned short* T3b = (unsigned short*)alloc((size_t)N * 40 * 2);

  // --- CSR build via bucket binning ---
  bucket_count<<<CB, 256, 0, stream>>>(dstp, partial, E);
  scan_pack<<<14, 256, 0, stream>>>(partial, gstart, gcur, row_ptr,
                                    W1, W2, W3, Wp1, Wp2, Wp3, NB, N, E);
  int E4 = E >> 2;
  int nbin = (E4 + ((E & 3) ? 1 : 0) + 511) / 512;
  bin_edges<<<nbin, 512, 0, stream>>>(srcp, dstp, gcur, packed, E, NB);
  build_local_csr<<<NB, 256, 0, stream>>>(packed, gstart, row_ptr, col, N);

  int rt4 = ((N + 15) / 16 + 3) / 4;
  int aggblocks = (N * 12 + 255) / 256;

  // Layer 1
  mfma_gemm<4, 6, true, true, 96, 96><<<dim3(rt4, 2), 256, 0, stream>>>(x, Wp1, Tb, N);
  agg_relu_bf16<<<aggblocks, 256, 0, stream>>>(Tb, row_ptr, col, b1, Hb, N);
  // Layer 2
  mfma_gemm<3, 6, false, true, 96, 96><<<dim3(rt4, 2), 256, 0, stream>>>(Hb, Wp2, Tb, N);
  agg_relu_bf16<<<aggblocks, 256, 0, stream>>>(Tb, row_ptr, col, b2, Hb, N);
  // Layer 3 + log_softmax
  mfma_gemm<3, 3, false, true, 40, 40><<<dim3(rt4, 1), 256, 0, stream>>>(Hb, Wp3, T3b, N);
  agg_lsm_bf16<<<(N + 15) / 16, 256, 0, stream>>>(T3b, row_ptr, col, b3, (float*)d_out, N);
}